// Round 9
// baseline (15.027 us; speedup 1.0000x reference)
//
#include <hip/hip_runtime.h>
#include <hip/hip_bf16.h>

// KAN layer, fully fused single kernel (one dispatch).
// y[b,o] = sum_kk F[b][kk] * Wt[o][kk], KK=2304, planar kk = n*256+d
// (n = 0..7: uniform cubic B-spline funcs, n=8: silu / base weight).
// 256 blocks x 1024 threads; block = 16b x 16o tile; operand tiles in LDS.
// F is built DENSELY per-thread (each thread owns its (row,d-pair) column
// across all 8 planes and writes packed b32 values, selecting m=i-n among
// the 4 nonzero basis polys) -- no zero-fill phase, no pre-barrier, loads
// issue at kernel top and pipeline into the select VALU.
// XCD-aware tile decode keeps each coef o-tile in ONE per-XCD L2.

#define KK 2304
#define RS 2312                      // row stride (elems): 16B-aligned rows
#define SMEM_BYTES (2*16*RS*2)       // F + W = 147968 B; reduce buf aliases F

typedef __attribute__((ext_vector_type(8))) short bf16x8;
typedef __attribute__((ext_vector_type(4))) float f32x4;

__device__ __forceinline__ unsigned short bfbits(float f) {
    __hip_bfloat16 h = __float2bfloat16(f);
    return *reinterpret_cast<unsigned short*>(&h);
}

__global__ __launch_bounds__(1024, 4) void kan_fused(
        const float* __restrict__ x, const float* __restrict__ grid,
        const float* __restrict__ coef, const float* __restrict__ sb,
        const float* __restrict__ ss, float* __restrict__ out) {
    extern __shared__ char smem[];
    __hip_bfloat16* ldsF = (__hip_bfloat16*)smem;                 // [16][RS]
    __hip_bfloat16* ldsW = (__hip_bfloat16*)(smem + 16*RS*2);     // [16][RS]
    unsigned* ldsFu = (unsigned*)ldsF;
    unsigned* ldsWu = (unsigned*)ldsW;

    // XCD-aware decode (bijective): XCD x = blk&7 owns o-tiles {2x, 2x+1}.
    int blk = blockIdx.x;
    int tc  = 2 * (blk & 7) + ((blk >> 7) & 1);   // o-tile
    int tr  = (blk >> 3) & 15;                    // b-tile
    int tid = threadIdx.x;

    float gl = grid[0], gr = grid[5];        // uniform knots (rows identical)
    float h  = (gr - gl) * 0.2f;
    float g0 = gl - 3.f * h;
    float inv_h = 1.f / h;

    // ---- Phase A: build F and W tiles, dense packed-b32 writes, no barrier
    // before (every LDS word is written by exactly one owner thread).
#pragma unroll
    for (int it = 0; it < 2; ++it) {
        int pidx = tid + it * 1024;          // 0..2047
        int row  = pidx >> 7;                // 0..15 (wave-uniform)
        int dp   = pidx & 127;
        int d0   = dp * 2;

        float2 xv2 = *(const float2*)(x + (tr * 16 + row) * 256 + d0);
        int s0 = (tc * 16 + row) * 256 + d0;
        const float4* cp = (const float4*)(coef + (size_t)s0 * 8);
        float4 a0 = cp[0], a1 = cp[1], c0 = cp[2], c1 = cp[3];
        float2 vb = *(const float2*)(sb + s0);
        float2 vs = *(const float2*)(ss + s0);

        // basis core per element
        const float k6 = 1.f / 6.f;
        float xs[2] = {xv2.x, xv2.y};
        float e_b0[2], e_b1[2], e_b2[2], e_b3[2];
        int   e_i[2];
        unsigned short sl[2];
#pragma unroll
        for (int e = 0; e < 2; ++e) {
            float xv = xs[e];
            float tt = (xv - g0) * inv_h;
            float fi = floorf(tt);
            e_i[e] = (int)fi;
            float u  = tt - fi;
            float u2 = u * u, u3 = u2 * u, um = 1.f - u;
            e_b3[e] = u3 * k6;                               // m=0 (plane i)
            e_b2[e] = (-3.f*u3 + 3.f*u2 + 3.f*u + 1.f) * k6; // m=1
            e_b1[e] = (3.f*u3 - 6.f*u2 + 4.f) * k6;          // m=2
            e_b0[e] = um * um * um * k6;                     // m=3
            sl[e] = bfbits(xv / (1.f + __expf(-xv)));        // silu
        }

        unsigned fbase = (unsigned)(row * (RS / 2) + dp);
        // dense plane writes: val_n = poly_{i-n}(u), 0 outside [0,3]
#pragma unroll
        for (int n = 0; n < 8; ++n) {
            unsigned short p0, p1;
            {
                int m = e_i[0] - n;
                float v = (m == 0) ? e_b3[0] : (m == 1) ? e_b2[0]
                        : (m == 2) ? e_b1[0] : (m == 3) ? e_b0[0] : 0.f;
                p0 = bfbits(v);
            }
            {
                int m = e_i[1] - n;
                float v = (m == 0) ? e_b3[1] : (m == 1) ? e_b2[1]
                        : (m == 2) ? e_b1[1] : (m == 3) ? e_b0[1] : 0.f;
                p1 = bfbits(v);
            }
            ldsFu[fbase + n * 128] = (unsigned)p0 | ((unsigned)p1 << 16);
        }
        ldsFu[fbase + 8 * 128] = (unsigned)sl[0] | ((unsigned)sl[1] << 16);

        // W: ss*coef (planes 0..7) + sb (plane 8), two s-rows packed b32
        float vsx = vs.x, vsy = vs.y;
        float wa[9] = {vsx*a0.x, vsx*a0.y, vsx*a0.z, vsx*a0.w,
                       vsx*a1.x, vsx*a1.y, vsx*a1.z, vsx*a1.w, vb.x};
        float wb[9] = {vsy*c0.x, vsy*c0.y, vsy*c0.z, vsy*c0.w,
                       vsy*c1.x, vsy*c1.y, vsy*c1.z, vsy*c1.w, vb.y};
#pragma unroll
        for (int n = 0; n < 9; ++n)
            ldsWu[fbase + n * 128] =
                (unsigned)bfbits(wa[n]) | ((unsigned)bfbits(wb[n]) << 16);
    }
    __syncthreads();

    // ---- Phase B: 16 waves over 72 k-steps of 32 (round-robin, 5/4 each)
    int lane = tid & 63, wave = tid >> 6;
    int r16 = lane & 15, kg = lane >> 4;
    const __hip_bfloat16* ap = ldsF + r16 * RS + kg * 8;
    const __hip_bfloat16* bp = ldsW + r16 * RS + kg * 8;
    f32x4 acc = {0.f, 0.f, 0.f, 0.f};
    for (int s = wave; s < 72; s += 16) {
        bf16x8 a = *reinterpret_cast<const bf16x8*>(ap + s * 32);
        bf16x8 b = *reinterpret_cast<const bf16x8*>(bp + s * 32);
        acc = __builtin_amdgcn_mfma_f32_16x16x32_bf16(a, b, acc, 0, 0, 0);
    }

    // ---- Epilogue: reduce 16 waves' partials (reduce buf aliases dead F)
    __syncthreads();                      // all waves done reading F
    float (*red)[64][4] = (float(*)[64][4])smem;   // [16][64][4] = 16 KB
    *(f32x4*)red[wave][lane] = acc;
    __syncthreads();
    if (tid < 256) {
        // thread -> (row, col) with col fastest => coalesced 64B row stores
        int row = tid >> 4, col = tid & 15;
        int l2 = (row >> 2) * 16 + col, j2 = row & 3;   // C-layout inverse
        float v = 0.f;
#pragma unroll
        for (int w = 0; w < 16; ++w) v += red[w][l2][j2];
        out[(size_t)(tr * 16 + row) * 256 + tc * 16 + col] = v;
    }
}

extern "C" void kernel_launch(void* const* d_in, const int* in_sizes, int n_in,
                              void* d_out, int out_size, void* d_ws, size_t ws_size,
                              hipStream_t stream) {
    const float* x    = (const float*)d_in[0];   // [256,256]
    const float* grid = (const float*)d_in[1];   // [65536,6] (rows identical)
    const float* coef = (const float*)d_in[2];   // [65536,8]
    const float* sb   = (const float*)d_in[3];   // [65536]
    const float* ss   = (const float*)d_in[4];   // [65536]
    float* out = (float*)d_out;                  // [256,256] f32

    kan_fused<<<256, 1024, SMEM_BYTES, stream>>>(x, grid, coef, sb, ss, out);
}

// Round 10
// 10.482 us; speedup vs baseline: 1.4335x; 1.4335x over previous
//
#include <hip/hip_runtime.h>
#include <hip/hip_bf16.h>

// KAN layer, fully fused single kernel (one dispatch).
// y[b,o] = sum_kk F[b][kk] * Wt[o][kk], KK=2304, planar kk = n*256+d
// (n = 0..7: uniform cubic B-spline funcs, n=8: silu / base weight).
// 256 blocks x 1024 threads; block = 16b x 16o tile; operand tiles in LDS.
// F build: per-thread zero (8 b32 words of own column) + 4 masked b16
// scatter overwrites -- same-wave DS ops to the same address complete in
// program order, so NO barrier is needed before the single pre-MFMA barrier,
// and global loads issue from cycle 0 (R7 lesson: never put loads before a
// barrier; R9 lesson: dense selects + extra bf16 converts spill VGPRs).
// XCD-aware tile decode keeps each coef o-tile in ONE per-XCD L2.

#define KK 2304
#define RS 2312                      // row stride (elems): 16B-aligned rows
#define SMEM_BYTES (2*16*RS*2)       // F + W = 147968 B; reduce buf aliases F

typedef __attribute__((ext_vector_type(8))) short bf16x8;
typedef __attribute__((ext_vector_type(4))) float f32x4;

__device__ __forceinline__ unsigned short bfbits(float f) {
    __hip_bfloat16 h = __float2bfloat16(f);
    return *reinterpret_cast<unsigned short*>(&h);
}

__global__ __launch_bounds__(1024, 4) void kan_fused(
        const float* __restrict__ x, const float* __restrict__ grid,
        const float* __restrict__ coef, const float* __restrict__ sb,
        const float* __restrict__ ss, float* __restrict__ out) {
    extern __shared__ char smem[];
    __hip_bfloat16* ldsF = (__hip_bfloat16*)smem;                 // [16][RS]
    __hip_bfloat16* ldsW = (__hip_bfloat16*)(smem + 16*RS*2);     // [16][RS]
    unsigned* ldsFu = (unsigned*)ldsF;
    unsigned* ldsWu = (unsigned*)ldsW;

    // XCD-aware decode (bijective): XCD x = blk&7 owns o-tiles {2x, 2x+1}.
    int blk = blockIdx.x;
    int tc  = 2 * (blk & 7) + ((blk >> 7) & 1);   // o-tile
    int tr  = (blk >> 3) & 15;                    // b-tile
    int tid = threadIdx.x;

    float gl = grid[0], gr = grid[5];        // uniform knots (rows identical)
    float h  = (gr - gl) * 0.2f;
    float g0 = gl - 3.f * h;
    float inv_h = 1.f / h;

    // ---- Phase A: build F and W tiles. No barrier before this phase:
    // every LDS word is written only by its owner thread.
#pragma unroll
    for (int it = 0; it < 2; ++it) {
        int pidx = tid + it * 1024;          // 0..2047
        int row  = pidx >> 7;                // 0..15 (wave-uniform)
        int dp   = pidx & 127;
        int d0   = dp * 2;

        float2 xv2 = *(const float2*)(x + (tr * 16 + row) * 256 + d0);
        int s0 = (tc * 16 + row) * 256 + d0;
        const float4* cp = (const float4*)(coef + (size_t)s0 * 8);
        float4 a0 = cp[0], a1 = cp[1], c0 = cp[2], c1 = cp[3];
        float2 vb = *(const float2*)(sb + s0);
        float2 vs = *(const float2*)(ss + s0);

        unsigned fbase = (unsigned)(row * (RS / 2) + dp);
        // zero this column's 8 basis-plane words (overwritten below by the
        // same thread -- same-wave DS ordering makes this barrier-free)
#pragma unroll
        for (int n = 0; n < 8; ++n) ldsFu[fbase + n * 128] = 0u;

        unsigned short sl[2];
        const float k6 = 1.f / 6.f;
        float xs[2] = {xv2.x, xv2.y};
#pragma unroll
        for (int e = 0; e < 2; ++e) {
            float xv = xs[e];
            float tt = (xv - g0) * inv_h;
            float fi = floorf(tt);
            int   i  = (int)fi;
            float u  = tt - fi;
            float u2 = u * u, u3 = u2 * u, um = 1.f - u;
            float b3 = u3 * k6;                               // plane i
            float b2 = (-3.f*u3 + 3.f*u2 + 3.f*u + 1.f) * k6; // plane i-1
            float b1 = (3.f*u3 - 6.f*u2 + 4.f) * k6;          // plane i-2
            float b0 = um * um * um * k6;                     // plane i-3
            __hip_bfloat16* base = ldsF + row * RS + d0 + e;
            float vals[4] = {b3, b2, b1, b0};
#pragma unroll
            for (int m = 0; m < 4; ++m) {
                int n = i - m;
                if ((unsigned)n <= 7u)                        // edge-masked
                    base[n * 256] = __float2bfloat16(vals[m]);
            }
            sl[e] = bfbits(xv / (1.f + __expf(-xv)));         // silu
        }
        // silu plane (8): packed b32, conflict-free
        ldsFu[fbase + 8 * 128] = (unsigned)sl[0] | ((unsigned)sl[1] << 16);

        // W: ss*coef (planes 0..7) + sb (plane 8), two s-rows packed b32
        float vsx = vs.x, vsy = vs.y;
        float wa[9] = {vsx*a0.x, vsx*a0.y, vsx*a0.z, vsx*a0.w,
                       vsx*a1.x, vsx*a1.y, vsx*a1.z, vsx*a1.w, vb.x};
        float wb[9] = {vsy*c0.x, vsy*c0.y, vsy*c0.z, vsy*c0.w,
                       vsy*c1.x, vsy*c1.y, vsy*c1.z, vsy*c1.w, vb.y};
#pragma unroll
        for (int n = 0; n < 9; ++n)
            ldsWu[fbase + n * 128] =
                (unsigned)bfbits(wa[n]) | ((unsigned)bfbits(wb[n]) << 16);
    }
    __syncthreads();

    // ---- Phase B: 16 waves over 72 k-steps of 32; fully unrolled
    // (4 fixed steps + 1 guarded for waves 0..7).
    int lane = tid & 63, wave = tid >> 6;
    int r16 = lane & 15, kg = lane >> 4;
    const __hip_bfloat16* ap = ldsF + r16 * RS + kg * 8;
    const __hip_bfloat16* bp = ldsW + r16 * RS + kg * 8;
    f32x4 acc = {0.f, 0.f, 0.f, 0.f};
#pragma unroll
    for (int j = 0; j < 4; ++j) {
        int s = wave + j * 16;
        bf16x8 a = *reinterpret_cast<const bf16x8*>(ap + s * 32);
        bf16x8 b = *reinterpret_cast<const bf16x8*>(bp + s * 32);
        acc = __builtin_amdgcn_mfma_f32_16x16x32_bf16(a, b, acc, 0, 0, 0);
    }
    if (wave < 8) {
        int s = wave + 64;
        bf16x8 a = *reinterpret_cast<const bf16x8*>(ap + s * 32);
        bf16x8 b = *reinterpret_cast<const bf16x8*>(bp + s * 32);
        acc = __builtin_amdgcn_mfma_f32_16x16x32_bf16(a, b, acc, 0, 0, 0);
    }

    // ---- Epilogue: reduce 16 waves' partials (reduce buf aliases dead F)
    __syncthreads();                      // all waves done reading F
    float (*red)[64][4] = (float(*)[64][4])smem;   // [16][64][4] = 16 KB
    *(f32x4*)red[wave][lane] = acc;
    __syncthreads();
    if (tid < 256) {
        // thread -> (row, col) with col fastest => coalesced 64B row stores
        int row = tid >> 4, col = tid & 15;
        int l2 = (row >> 2) * 16 + col, j2 = row & 3;   // C-layout inverse
        float v = 0.f;
#pragma unroll
        for (int w = 0; w < 16; ++w) v += red[w][l2][j2];
        out[(size_t)(tr * 16 + row) * 256 + tc * 16 + col] = v;
    }
}

extern "C" void kernel_launch(void* const* d_in, const int* in_sizes, int n_in,
                              void* d_out, int out_size, void* d_ws, size_t ws_size,
                              hipStream_t stream) {
    const float* x    = (const float*)d_in[0];   // [256,256]
    const float* grid = (const float*)d_in[1];   // [65536,6] (rows identical)
    const float* coef = (const float*)d_in[2];   // [65536,8]
    const float* sb   = (const float*)d_in[3];   // [65536]
    const float* ss   = (const float*)d_in[4];   // [65536]
    float* out = (float*)d_out;                  // [256,256] f32

    kan_fused<<<256, 1024, SMEM_BYTES, stream>>>(x, grid, coef, sb, ss, out);
}